// Round 1
// baseline (218.816 us; speedup 1.0000x reference)
//
#include <hip/hip_runtime.h>

// SoftEmbeddedDecisionRules: balanced binary hierarchy over C=1024 classes.
// out[b,c] = prod over 10 levels of softmax-over-2-children prob of the branch
// containing c, where child logit = mean of raw logits over the child's block.
// softmax over 2 == sigmoid(diff of means) -> build binary sum tree, one
// sigmoid per internal node, 10-term product per class.

#define C 1024

__global__ __launch_bounds__(256) void hier_softmax_kernel(
    const float* __restrict__ in, float* __restrict__ out) {
    // heap over 256 depth-8 block sums: heap[1..255] internal, heap[256..511] leaves
    __shared__ float heap[512];
    __shared__ float pleft[256];  // pleft[n]: prob of LEFT child of internal node n (1..255)

    const int row = blockIdx.x;
    const int tid = threadIdx.x;

    const float4 v = ((const float4*)(in + (size_t)row * C))[tid];

    // bottom two levels in registers
    const float s2a = v.x + v.y;   // pair sums (depth-9 blocks, seg=2)
    const float s2b = v.z + v.w;
    const float s4  = s2a + s2b;   // depth-8 block sum (seg=4)
    heap[256 + tid] = s4;
    __syncthreads();

    // upsweep: cnt nodes at this level; their children cover seg = 512/cnt classes
    for (int cnt = 128; cnt >= 1; cnt >>= 1) {
        if (tid < cnt) {
            const int n = cnt + tid;
            const float a = heap[2 * n];
            const float b = heap[2 * n + 1];
            heap[n] = a + b;
            const float inv_seg = (float)cnt * (1.0f / 512.0f);
            // p(left) = sigmoid((mean_a - mean_b)) = 1/(1+exp((b-a)/seg))
            pleft[n] = 1.0f / (1.0f + __expf((b - a) * inv_seg));
        }
        __syncthreads();
    }

    // product of branch probs for depths 1..8 (shared by this thread's 4 classes)
    float common = 1.0f;
    const int leaf = 256 + tid;
#pragma unroll
    for (int s = 7; s >= 0; --s) {
        const int m = leaf >> s;          // ancestor at depth 8-s
        const float p = pleft[m >> 1];
        common *= (m & 1) ? (1.0f - p) : p;
    }

    // depth 9 (pairs-of-pairs) and depth 10 (adjacent classes) from registers
    const float p9 = 1.0f / (1.0f + __expf((s2b - s2a) * 0.5f));
    const float pA = 1.0f / (1.0f + __expf(v.y - v.x));
    const float pB = 1.0f / (1.0f + __expf(v.w - v.z));

    const float cl = common * p9;
    const float cr = common * (1.0f - p9);
    float4 o;
    o.x = cl * pA;
    o.y = cl * (1.0f - pA);
    o.z = cr * pB;
    o.w = cr * (1.0f - pB);
    ((float4*)(out + (size_t)row * C))[tid] = o;
}

extern "C" void kernel_launch(void* const* d_in, const int* in_sizes, int n_in,
                              void* d_out, int out_size, void* d_ws, size_t ws_size,
                              hipStream_t stream) {
    const float* in = (const float*)d_in[0];
    float* out = (float*)d_out;
    const int B = in_sizes[0] / C;  // 32768
    hier_softmax_kernel<<<B, 256, 0, stream>>>(in, out);
}